// Round 3
// baseline (192.851 us; speedup 1.0000x reference)
//
#include <hip/hip_runtime.h>
#include <hip/hip_bf16.h>
#include <math.h>

// Problem: B=4, L=2048 (M = 8192 rows), D_MODEL = 768, N_STATE = 16.
// y[row,d] = x[row,d] * softplus((x@W1+b1)[row,d]) * dot(x@W2+b2, x@W3+b3)[row]
// (dA*h0 term is identically zero; A unused.)

#define M_ROWS 8192
#define DM 768
#define NS 16

typedef short bf16x8 __attribute__((ext_vector_type(8)));
typedef float f32x4 __attribute__((ext_vector_type(4)));

__device__ __forceinline__ unsigned short f2bf(float f) {
    union { float f; unsigned u; } v; v.f = f;
    unsigned r = v.u + 0x7FFF + ((v.u >> 16) & 1);   // RNE
    return (unsigned short)(r >> 16);
}
__device__ __forceinline__ float bf2f(unsigned short h) {
    union { unsigned u; float f; } v; v.u = ((unsigned)h) << 16; return v.f;
}
__device__ __forceinline__ void async16(const void* g, void* l) {
    __builtin_amdgcn_global_load_lds(
        (const __attribute__((address_space(1))) void*)g,
        (__attribute__((address_space(3))) void*)l,
        16, 0, 0);
}

// ---- kernel 1: block-specialized prep -----------------------------------
// bid [0,128):        s[row] = dot(x@W2+b2, x@W3+b3); 16 rows/wave,
//                     lane = (rowgroup, n4): every W2/W3 load = one dense
//                     64B line broadcast across rowgroups (no 64B-stride
//                     scatter, no per-row redundancy blowup).
// bid [128,6272):     streaming convert x -> xb (bf16), float4 per thread.
// bid [6272,6848):    W1 [k][n] fp32 -> w1t [n][k] bf16 (32x32 LDS tiles).
__global__ __launch_bounds__(256) void prep_kernel(
    const float* __restrict__ x,
    const float* __restrict__ W1,
    const float* __restrict__ W2, const float* __restrict__ b2,
    const float* __restrict__ W3, const float* __restrict__ b3,
    unsigned short* __restrict__ xb,
    unsigned short* __restrict__ w1t,
    float* __restrict__ s_out)
{
    __shared__ float tile[32][33];
    const int bid = blockIdx.x;
    const int tid = threadIdx.x;
    if (bid < 128) {
        // ---- s computation: 64 rows per block, 16 per wave ----
        const int wave = tid >> 6, lane = tid & 63;
        const int row = bid * 64 + wave * 16 + (lane >> 2);
        const int n4 = (lane & 3) * 4;           // this lane's 4 n-columns
        const float4* xr = (const float4*)(x + row * DM);
        const float4* w2p = (const float4*)(W2 + n4);   // stride NS floats
        const float4* w3p = (const float4*)(W3 + n4);
        float4 aB = {0.f,0.f,0.f,0.f}, aC = {0.f,0.f,0.f,0.f};
        #pragma unroll 4
        for (int d4 = 0; d4 < DM / 4; ++d4) {
            float4 xv = xr[d4];
            int base = d4 * 4 * (NS / 4);        // row d4*4 of W2 in float4s
            float4 w20 = w2p[base];      float4 w30 = w3p[base];
            float4 w21 = w2p[base + 4];  float4 w31 = w3p[base + 4];
            float4 w22 = w2p[base + 8];  float4 w32 = w3p[base + 8];
            float4 w23 = w2p[base + 12]; float4 w33 = w3p[base + 12];
            aB.x += xv.x*w20.x + xv.y*w21.x + xv.z*w22.x + xv.w*w23.x;
            aB.y += xv.x*w20.y + xv.y*w21.y + xv.z*w22.y + xv.w*w23.y;
            aB.z += xv.x*w20.z + xv.y*w21.z + xv.z*w22.z + xv.w*w23.z;
            aB.w += xv.x*w20.w + xv.y*w21.w + xv.z*w22.w + xv.w*w23.w;
            aC.x += xv.x*w30.x + xv.y*w31.x + xv.z*w32.x + xv.w*w33.x;
            aC.y += xv.x*w30.y + xv.y*w31.y + xv.z*w32.y + xv.w*w33.y;
            aC.z += xv.x*w30.z + xv.y*w31.z + xv.z*w32.z + xv.w*w33.z;
            aC.w += xv.x*w30.w + xv.y*w31.w + xv.z*w32.w + xv.w*w33.w;
        }
        float4 bB = ((const float4*)b2)[lane & 3];
        float4 bC = ((const float4*)b3)[lane & 3];
        float p = (aB.x + bB.x) * (aC.x + bC.x)
                + (aB.y + bB.y) * (aC.y + bC.y)
                + (aB.z + bB.z) * (aC.z + bC.z)
                + (aB.w + bB.w) * (aC.w + bC.w);
        p += __shfl_xor(p, 1, 64);
        p += __shfl_xor(p, 2, 64);
        if ((lane & 3) == 0) s_out[row] = p;
    } else if (bid < 128 + 6144) {
        // ---- streaming x -> xb ----
        int i = (bid - 128) * 256 + tid;         // one float4 per thread
        float4 v = ((const float4*)x)[i];
        ushort4 o;
        o.x = f2bf(v.x); o.y = f2bf(v.y); o.z = f2bf(v.z); o.w = f2bf(v.w);
        ((ushort4*)xb)[i] = o;
    } else {
        // ---- W1 transpose to bf16 n-major ----
        const int b2i = bid - (128 + 6144);      // 0..575
        const int n0 = (b2i % 24) * 32, k0 = (b2i / 24) * 32;
        const int tx = tid & 31, ty = tid >> 5;  // 32 x 8
        #pragma unroll
        for (int i = 0; i < 4; ++i) {
            int k = ty + i * 8;
            tile[k][tx] = W1[(k0 + k) * DM + n0 + tx];
        }
        __syncthreads();
        #pragma unroll
        for (int i = 0; i < 4; ++i) {
            int n = ty + i * 8;
            w1t[(n0 + n) * DM + k0 + tx] = f2bf(tile[tx][n]);
        }
    }
}

// ---- kernel 2: fused bf16 MFMA GEMM + softplus/scale epilogue -----------
// 64x64 block tile, BK=64, 4 waves (2x2), wave = 2x2 of 16x16x32 MFMA.
// 1536 blocks, XCD-aware mapping: XCD c (= b&7, assuming round-robin
// dispatch) covers m-tiles [c*16, c*16+16) x all 12 n-tiles, so each
// A-tile is read once from L3 and 11 more times from the XCD's L2.
// LDS rows are 128 B; 16B chunks XOR-swizzled (j ^ (row&7)) on the global
// source of global_load_lds, mirrored in ds_read addressing.
__global__ __launch_bounds__(256) void gemm_fused_kernel(
    const unsigned short* __restrict__ xb,    // [8192][768] bf16
    const unsigned short* __restrict__ w1t,   // [768][768] bf16, n-major
    const float* __restrict__ b1,
    const float* __restrict__ s_arr,
    float* __restrict__ y)
{
    __shared__ unsigned short Al[64 * 64];
    __shared__ unsigned short Bl[64 * 64];
    const int b = blockIdx.x;
    const int c = b & 7, j = b >> 3;
    const int m0 = (c * 16 + j / 12) * 64;
    const int n0 = (j % 12) * 64;
    const int tid  = threadIdx.x;
    const int lane = tid & 63;
    const int wave = tid >> 6;
    const int wm = wave >> 1, wn = wave & 1;
    const int l15 = lane & 15, quad = lane >> 4;

    f32x4 acc[2][2];
    #pragma unroll
    for (int i = 0; i < 2; ++i)
        #pragma unroll
        for (int jj = 0; jj < 2; ++jj)
            acc[i][jj] = (f32x4){0.f, 0.f, 0.f, 0.f};

    for (int k0 = 0; k0 < DM; k0 += 64) {
        #pragma unroll
        for (int i = 0; i < 2; ++i) {
            int ch = tid + i * 256;       // lds chunk, lane-contiguous
            int r = ch >> 3;              // tile row
            int jl = ch & 7;              // lds chunk-in-row
            int jg = jl ^ (r & 7);        // swizzled global chunk
            async16(xb  + (m0 + r) * DM + k0 + jg * 8, Al + ch * 8);
            async16(w1t + (n0 + r) * DM + k0 + jg * 8, Bl + ch * 8);
        }
        __syncthreads();

        bf16x8 af[2][2], bq[2][2];
        #pragma unroll
        for (int i = 0; i < 2; ++i) {
            #pragma unroll
            for (int kk = 0; kk < 2; ++kk) {
                int rr = wm * 32 + i * 16 + l15;
                int ja = (kk * 4 + quad) ^ (rr & 7);
                af[i][kk] = *(const bf16x8*)(Al + rr * 64 + ja * 8);
                int rb = wn * 32 + i * 16 + l15;
                int jb = (kk * 4 + quad) ^ (rb & 7);
                bq[i][kk] = *(const bf16x8*)(Bl + rb * 64 + jb * 8);
            }
        }
        #pragma unroll
        for (int kk = 0; kk < 2; ++kk)
            #pragma unroll
            for (int i = 0; i < 2; ++i)
                #pragma unroll
                for (int jj = 0; jj < 2; ++jj)
                    acc[i][jj] = __builtin_amdgcn_mfma_f32_16x16x32_bf16(
                        af[i][kk], bq[jj][kk], acc[i][jj], 0, 0, 0);
        __syncthreads();
    }

    // epilogue: C/D layout col = lane&15, row = quad*4 + reg
    #pragma unroll
    for (int i = 0; i < 2; ++i) {
        #pragma unroll
        for (int jj = 0; jj < 2; ++jj) {
            int gcol = n0 + wn * 32 + jj * 16 + l15;
            float bias = b1[gcol];
            #pragma unroll
            for (int r = 0; r < 4; ++r) {
                int grow = m0 + wm * 32 + i * 16 + quad * 4 + r;
                float v = acc[i][jj][r] + bias;
                float sp = (v > 20.f) ? v : log1pf(__expf(v));
                float xv = bf2f(xb[grow * DM + gcol]);
                y[grow * DM + gcol] = xv * sp * s_arr[grow];
            }
        }
    }
}

extern "C" void kernel_launch(void* const* d_in, const int* in_sizes, int n_in,
                              void* d_out, int out_size, void* d_ws, size_t ws_size,
                              hipStream_t stream) {
    const float* x  = (const float*)d_in[0];
    const float* W1 = (const float*)d_in[1];
    const float* b1 = (const float*)d_in[2];
    const float* W2 = (const float*)d_in[3];
    const float* b2 = (const float*)d_in[4];
    const float* W3 = (const float*)d_in[5];
    const float* b3 = (const float*)d_in[6];
    // d_in[7] = A : unused (multiplied by h0 == 0 in the reference)
    float* y = (float*)d_out;

    unsigned short* xb   = (unsigned short*)d_ws;                      // 12,582,912 B
    unsigned short* w1t  = (unsigned short*)((char*)d_ws + 12582912);  //  1,179,648 B
    float*          sarr = (float*)((char*)d_ws + 13762560);           //     32,768 B

    prep_kernel<<<128 + 6144 + 576, 256, 0, stream>>>(x, W1, W2, b2, W3, b3,
                                                      xb, w1t, sarr);
    gemm_fused_kernel<<<1536, 256, 0, stream>>>(xb, w1t, b1, sarr, y);
}

// Round 4
// 136.717 us; speedup vs baseline: 1.4106x; 1.4106x over previous
//
#include <hip/hip_runtime.h>
#include <hip/hip_bf16.h>
#include <math.h>

// Problem: B=4, L=2048 (M = 8192 rows), D_MODEL = 768, N_STATE = 16.
// y[row,d] = x[row,d] * softplus((x@W1+b1)[row,d]) * dot(x@W2+b2, x@W3+b3)[row]
// (dA*h0 term is identically zero; A unused.)

#define M_ROWS 8192
#define DM 768
#define NS 16

typedef short bf16x8 __attribute__((ext_vector_type(8)));
typedef float f32x4 __attribute__((ext_vector_type(4)));

__device__ __forceinline__ unsigned short f2bf(float f) {
    union { float f; unsigned u; } v; v.f = f;
    unsigned r = v.u + 0x7FFF + ((v.u >> 16) & 1);   // RNE
    return (unsigned short)(r >> 16);
}
__device__ __forceinline__ float bf2f(unsigned short h) {
    union { unsigned u; float f; } v; v.u = ((unsigned)h) << 16; return v.f;
}
__device__ __forceinline__ void async16(const void* g, void* l) {
    __builtin_amdgcn_global_load_lds(
        (const __attribute__((address_space(1))) void*)g,
        (__attribute__((address_space(3))) void*)l,
        16, 0, 0);
}

// ---- kernel 1: prep (pure streaming, block-specialized) ------------------
// bid [0,32):      w23t build: row n (bf16, n-major, 768 k). Even rows =
//                  W2 col n/2, odd = W3 col n/2 (pair-interleaved so the
//                  s-GEMM C-tile has product pairs in adjacent lanes).
// bid [32,608):    W1 [k][n] fp32 -> w1t [n][k] bf16 (32x32 LDS tiles).
// bid [608,6752):  streaming convert x -> xb (bf16), float4/thread.
__global__ __launch_bounds__(256) void prep_kernel(
    const float* __restrict__ x,
    const float* __restrict__ W1,
    const float* __restrict__ W2,
    const float* __restrict__ W3,
    unsigned short* __restrict__ xb,
    unsigned short* __restrict__ w1t,
    unsigned short* __restrict__ w23t)
{
    __shared__ float tile[32][33];
    const int bid = blockIdx.x;
    const int tid = threadIdx.x;
    if (bid < 32) {
        const int n = bid, i = n >> 1;
        const float* src = (n & 1) ? W3 : W2;
        #pragma unroll
        for (int e = 0; e < 3; ++e) {
            int k = e * 256 + tid;
            w23t[n * DM + k] = f2bf(src[k * NS + i]);
        }
    } else if (bid < 608) {
        const int b2i = bid - 32;                // 0..575
        const int n0 = (b2i % 24) * 32, k0 = (b2i / 24) * 32;
        const int tx = tid & 31, ty = tid >> 5;  // 32 x 8
        #pragma unroll
        for (int i = 0; i < 4; ++i) {
            int k = ty + i * 8;
            tile[k][tx] = W1[(k0 + k) * DM + n0 + tx];
        }
        __syncthreads();
        #pragma unroll
        for (int i = 0; i < 4; ++i) {
            int n = ty + i * 8;
            w1t[(n0 + n) * DM + k0 + tx] = f2bf(tile[tx][n]);
        }
    } else {
        int i = (bid - 608) * 256 + tid;         // one float4 per thread
        float4 v = ((const float4*)x)[i];
        ushort4 o;
        o.x = f2bf(v.x); o.y = f2bf(v.y); o.z = f2bf(v.z); o.w = f2bf(v.w);
        ((ushort4*)xb)[i] = o;
    }
}

// ---- kernel 2: s via MFMA ------------------------------------------------
// P = xb @ w23t^T (8192 x 32), s[row] = sum_p (P[row,2p]+b2[p])*(P[row,2p+1]+b3[p]).
// 128 blocks x 64 rows; 4 waves, wave = 16 rows x 32 cols (2 n-tiles).
// Pair product via shfl_xor(1) (both pair lanes compute the same term ->
// 16-lane xor-reduce double-counts -> *0.5).
__global__ __launch_bounds__(256) void sgemm_kernel(
    const unsigned short* __restrict__ xb,
    const unsigned short* __restrict__ w23t,
    const float* __restrict__ b2, const float* __restrict__ b3,
    float* __restrict__ s_out)
{
    __shared__ unsigned short Al[64 * 64];
    __shared__ unsigned short Bl[32 * 64];
    const int m0 = blockIdx.x * 64;
    const int tid = threadIdx.x, lane = tid & 63, wave = tid >> 6;
    const int l15 = lane & 15, quad = lane >> 4;

    f32x4 acc[2];
    acc[0] = (f32x4){0.f,0.f,0.f,0.f};
    acc[1] = (f32x4){0.f,0.f,0.f,0.f};

    for (int k0 = 0; k0 < DM; k0 += 64) {
        #pragma unroll
        for (int i = 0; i < 2; ++i) {
            int ch = tid + i * 256;              // [0,512)
            int r = ch >> 3, jg = (ch & 7) ^ (r & 7);
            async16(xb + (m0 + r) * DM + k0 + jg * 8, Al + ch * 8);
        }
        {
            int ch = tid;                        // [0,256)
            int r = ch >> 3, jg = (ch & 7) ^ (r & 7);
            async16(w23t + r * DM + k0 + jg * 8, Bl + ch * 8);
        }
        __syncthreads();
        #pragma unroll
        for (int kk = 0; kk < 2; ++kk) {
            int rr = wave * 16 + l15;
            int ja = (kk * 4 + quad) ^ (rr & 7);
            bf16x8 af = *(const bf16x8*)(Al + rr * 64 + ja * 8);
            #pragma unroll
            for (int t = 0; t < 2; ++t) {
                int rb = t * 16 + l15;
                int jb = (kk * 4 + quad) ^ (rb & 7);
                bf16x8 bfr = *(const bf16x8*)(Bl + rb * 64 + jb * 8);
                acc[t] = __builtin_amdgcn_mfma_f32_16x16x32_bf16(
                    af, bfr, acc[t], 0, 0, 0);
            }
        }
        __syncthreads();
    }

    float sacc[4] = {0.f, 0.f, 0.f, 0.f};
    #pragma unroll
    for (int t = 0; t < 2; ++t) {
        int p = t * 8 + (l15 >> 1);
        float bB = b2[p], bC = b3[p];
        #pragma unroll
        for (int r = 0; r < 4; ++r) {
            float v = acc[t][r];
            float pv = __shfl_xor(v, 1, 64);
            float term = (l15 & 1) ? (pv + bB) * (v + bC)
                                   : (v + bB) * (pv + bC);
            sacc[r] += term;
        }
    }
    #pragma unroll
    for (int r = 0; r < 4; ++r) {
        sacc[r] += __shfl_xor(sacc[r], 1, 64);
        sacc[r] += __shfl_xor(sacc[r], 2, 64);
        sacc[r] += __shfl_xor(sacc[r], 4, 64);
        sacc[r] += __shfl_xor(sacc[r], 8, 64);
    }
    if (l15 == 0) {
        #pragma unroll
        for (int r = 0; r < 4; ++r)
            s_out[m0 + wave * 16 + quad * 4 + r] = 0.5f * sacc[r];
    }
}

// ---- kernel 3: fused bf16 MFMA GEMM + softplus/scale epilogue -----------
// 128x64 tile (m x n), BK=64, 768 blocks (3/CU). 4 waves 2x2; wave = 4x2
// MFMA tiles -> 16 MFMA per 24 KB staged per k-step (2x R2 density).
// XCD swizzle: XCD c (= b&7) covers m-tiles [c*8,c*8+8) x all 12 n-tiles.
__global__ __launch_bounds__(256) void gemm_fused_kernel(
    const unsigned short* __restrict__ xb,    // [8192][768] bf16
    const unsigned short* __restrict__ w1t,   // [768][768] bf16, n-major
    const float* __restrict__ b1,
    const float* __restrict__ s_arr,
    float* __restrict__ y)
{
    __shared__ unsigned short Al[128 * 64];   // 16 KB
    __shared__ unsigned short Bl[64 * 64];    //  8 KB
    const int b = blockIdx.x;
    const int c = b & 7, j = b >> 3;          // j in [0,96)
    const int m0 = (c * 8 + j / 12) * 128;
    const int n0 = (j % 12) * 64;
    const int tid  = threadIdx.x;
    const int lane = tid & 63;
    const int wave = tid >> 6;
    const int wm = wave >> 1, wn = wave & 1;
    const int l15 = lane & 15, quad = lane >> 4;

    f32x4 acc[4][2];
    #pragma unroll
    for (int i = 0; i < 4; ++i)
        #pragma unroll
        for (int jj = 0; jj < 2; ++jj)
            acc[i][jj] = (f32x4){0.f, 0.f, 0.f, 0.f};

    for (int k0 = 0; k0 < DM; k0 += 64) {
        #pragma unroll
        for (int i = 0; i < 4; ++i) {
            int ch = tid + i * 256;           // [0,1024)
            int r = ch >> 3, jg = (ch & 7) ^ (r & 7);
            async16(xb + (m0 + r) * DM + k0 + jg * 8, Al + ch * 8);
        }
        #pragma unroll
        for (int i = 0; i < 2; ++i) {
            int ch = tid + i * 256;           // [0,512)
            int r = ch >> 3, jg = (ch & 7) ^ (r & 7);
            async16(w1t + (n0 + r) * DM + k0 + jg * 8, Bl + ch * 8);
        }
        __syncthreads();

        #pragma unroll
        for (int kk = 0; kk < 2; ++kk) {
            bf16x8 bfr[2];
            #pragma unroll
            for (int jj = 0; jj < 2; ++jj) {
                int rb = wn * 32 + jj * 16 + l15;
                int jb = (kk * 4 + quad) ^ (rb & 7);
                bfr[jj] = *(const bf16x8*)(Bl + rb * 64 + jb * 8);
            }
            #pragma unroll
            for (int i = 0; i < 4; ++i) {
                int rr = wm * 64 + i * 16 + l15;
                int ja = (kk * 4 + quad) ^ (rr & 7);
                bf16x8 af = *(const bf16x8*)(Al + rr * 64 + ja * 8);
                #pragma unroll
                for (int jj = 0; jj < 2; ++jj)
                    acc[i][jj] = __builtin_amdgcn_mfma_f32_16x16x32_bf16(
                        af, bfr[jj], acc[i][jj], 0, 0, 0);
            }
        }
        __syncthreads();
    }

    // epilogue: C/D layout col = lane&15, row = quad*4 + reg
    #pragma unroll
    for (int i = 0; i < 4; ++i) {
        const int rowbase = m0 + wm * 64 + i * 16 + quad * 4;
        float4 s4 = *(const float4*)(s_arr + rowbase);
        #pragma unroll
        for (int jj = 0; jj < 2; ++jj) {
            int gcol = n0 + wn * 32 + jj * 16 + l15;
            float bias = b1[gcol];
            #pragma unroll
            for (int r = 0; r < 4; ++r) {
                int grow = rowbase + r;
                float v = acc[i][jj][r] + bias;
                float sp = (v > 20.f) ? v : log1pf(__expf(v));
                float xv = bf2f(xb[grow * DM + gcol]);
                float sv = (r == 0) ? s4.x : (r == 1) ? s4.y : (r == 2) ? s4.z : s4.w;
                y[grow * DM + gcol] = xv * sp * sv;
            }
        }
    }
}

extern "C" void kernel_launch(void* const* d_in, const int* in_sizes, int n_in,
                              void* d_out, int out_size, void* d_ws, size_t ws_size,
                              hipStream_t stream) {
    const float* x  = (const float*)d_in[0];
    const float* W1 = (const float*)d_in[1];
    const float* b1 = (const float*)d_in[2];
    const float* W2 = (const float*)d_in[3];
    const float* b2 = (const float*)d_in[4];
    const float* W3 = (const float*)d_in[5];
    const float* b3 = (const float*)d_in[6];
    // d_in[7] = A : unused (multiplied by h0 == 0 in the reference)
    float* y = (float*)d_out;

    unsigned short* xb   = (unsigned short*)d_ws;                      // 12,582,912 B
    unsigned short* w1t  = (unsigned short*)((char*)d_ws + 12582912);  //  1,179,648 B
    unsigned short* w23t = (unsigned short*)((char*)d_ws + 13762560);  //     49,152 B
    float*          sarr = (float*)((char*)d_ws + 13811712);           //     32,768 B

    prep_kernel<<<6752, 256, 0, stream>>>(x, W1, W2, W3, xb, w1t, w23t);
    sgemm_kernel<<<128, 256, 0, stream>>>(xb, w23t, b2, b3, sarr);
    gemm_fused_kernel<<<768, 256, 0, stream>>>(xb, w1t, b1, sarr, y);
}

// Round 5
// 135.797 us; speedup vs baseline: 1.4201x; 1.0068x over previous
//
#include <hip/hip_runtime.h>
#include <hip/hip_bf16.h>
#include <math.h>

// Problem: B=4, L=2048 (M = 8192 rows), D_MODEL = 768, N_STATE = 16.
// y[row,d] = x[row,d] * softplus((x@W1+b1)[row,d]) * dot(x@W2+b2, x@W3+b3)[row]
// (dA*h0 term is identically zero; A unused.)
// Note: timed window carries ~61 us of harness overhead (d_ws 268 MB 0xAA
// re-poison + input restores) -- kernel-side floor is ~61 + ~25.

#define M_ROWS 8192
#define DM 768
#define NS 16

typedef short bf16x8 __attribute__((ext_vector_type(8)));
typedef float f32x4 __attribute__((ext_vector_type(4)));

__device__ __forceinline__ unsigned short f2bf(float f) {
    union { float f; unsigned u; } v; v.f = f;
    unsigned r = v.u + 0x7FFF + ((v.u >> 16) & 1);   // RNE
    return (unsigned short)(r >> 16);
}
__device__ __forceinline__ float bf2f(unsigned short h) {
    union { unsigned u; float f; } v; v.u = ((unsigned)h) << 16; return v.f;
}
__device__ __forceinline__ void async16(const void* g, void* l) {
    __builtin_amdgcn_global_load_lds(
        (const __attribute__((address_space(1))) void*)g,
        (__attribute__((address_space(3))) void*)l,
        16, 0, 0);
}

// ---- kernel 1: prep (pure streaming, block-specialized) ------------------
__global__ __launch_bounds__(256) void prep_kernel(
    const float* __restrict__ x,
    const float* __restrict__ W1,
    const float* __restrict__ W2,
    const float* __restrict__ W3,
    unsigned short* __restrict__ xb,
    unsigned short* __restrict__ w1t,
    unsigned short* __restrict__ w23t)
{
    __shared__ float tile[32][33];
    const int bid = blockIdx.x;
    const int tid = threadIdx.x;
    if (bid < 32) {
        const int n = bid, i = n >> 1;
        const float* src = (n & 1) ? W3 : W2;
        #pragma unroll
        for (int e = 0; e < 3; ++e) {
            int k = e * 256 + tid;
            w23t[n * DM + k] = f2bf(src[k * NS + i]);
        }
    } else if (bid < 608) {
        const int b2i = bid - 32;                // 0..575
        const int n0 = (b2i % 24) * 32, k0 = (b2i / 24) * 32;
        const int tx = tid & 31, ty = tid >> 5;  // 32 x 8
        #pragma unroll
        for (int i = 0; i < 4; ++i) {
            int k = ty + i * 8;
            tile[k][tx] = W1[(k0 + k) * DM + n0 + tx];
        }
        __syncthreads();
        #pragma unroll
        for (int i = 0; i < 4; ++i) {
            int n = ty + i * 8;
            w1t[(n0 + n) * DM + k0 + tx] = f2bf(tile[tx][n]);
        }
    } else {
        int i = (bid - 608) * 256 + tid;         // one float4 per thread
        float4 v = ((const float4*)x)[i];
        ushort4 o;
        o.x = f2bf(v.x); o.y = f2bf(v.y); o.z = f2bf(v.z); o.w = f2bf(v.w);
        ((ushort4*)xb)[i] = o;
    }
}

// ---- kernel 2: s via MFMA (unchanged from R4 -- verified) ----------------
__global__ __launch_bounds__(256) void sgemm_kernel(
    const unsigned short* __restrict__ xb,
    const unsigned short* __restrict__ w23t,
    const float* __restrict__ b2, const float* __restrict__ b3,
    float* __restrict__ s_out)
{
    __shared__ unsigned short Al[64 * 64];
    __shared__ unsigned short Bl[32 * 64];
    const int m0 = blockIdx.x * 64;
    const int tid = threadIdx.x, lane = tid & 63, wave = tid >> 6;
    const int l15 = lane & 15, quad = lane >> 4;

    f32x4 acc[2];
    acc[0] = (f32x4){0.f,0.f,0.f,0.f};
    acc[1] = (f32x4){0.f,0.f,0.f,0.f};

    for (int k0 = 0; k0 < DM; k0 += 64) {
        #pragma unroll
        for (int i = 0; i < 2; ++i) {
            int ch = tid + i * 256;
            int r = ch >> 3, jg = (ch & 7) ^ (r & 7);
            async16(xb + (m0 + r) * DM + k0 + jg * 8, Al + ch * 8);
        }
        {
            int ch = tid;
            int r = ch >> 3, jg = (ch & 7) ^ (r & 7);
            async16(w23t + r * DM + k0 + jg * 8, Bl + ch * 8);
        }
        __syncthreads();
        #pragma unroll
        for (int kk = 0; kk < 2; ++kk) {
            int rr = wave * 16 + l15;
            int ja = (kk * 4 + quad) ^ (rr & 7);
            bf16x8 af = *(const bf16x8*)(Al + rr * 64 + ja * 8);
            #pragma unroll
            for (int t = 0; t < 2; ++t) {
                int rb = t * 16 + l15;
                int jb = (kk * 4 + quad) ^ (rb & 7);
                bf16x8 bfr = *(const bf16x8*)(Bl + rb * 64 + jb * 8);
                acc[t] = __builtin_amdgcn_mfma_f32_16x16x32_bf16(
                    af, bfr, acc[t], 0, 0, 0);
            }
        }
        __syncthreads();
    }

    float sacc[4] = {0.f, 0.f, 0.f, 0.f};
    #pragma unroll
    for (int t = 0; t < 2; ++t) {
        int p = t * 8 + (l15 >> 1);
        float bB = b2[p], bC = b3[p];
        #pragma unroll
        for (int r = 0; r < 4; ++r) {
            float v = acc[t][r];
            float pv = __shfl_xor(v, 1, 64);
            float term = (l15 & 1) ? (pv + bB) * (v + bC)
                                   : (v + bB) * (pv + bC);
            sacc[r] += term;
        }
    }
    #pragma unroll
    for (int r = 0; r < 4; ++r) {
        sacc[r] += __shfl_xor(sacc[r], 1, 64);
        sacc[r] += __shfl_xor(sacc[r], 2, 64);
        sacc[r] += __shfl_xor(sacc[r], 4, 64);
        sacc[r] += __shfl_xor(sacc[r], 8, 64);
    }
    if (l15 == 0) {
        #pragma unroll
        for (int r = 0; r < 4; ++r)
            s_out[m0 + wave * 16 + quad * 4 + r] = 0.5f * sacc[r];
    }
}

// ---- kernel 3: fused GEMM, double-buffered single-barrier k-loop --------
// 128x64 tile, BK=64, 768 blocks, LDS 48 KB -> 3 blocks/CU (12 waves/CU).
// Prefetch for step k+1 issues AFTER the barrier and BEFORE compute(k), so
// the vmcnt(0) drain at barrier(k+1) waits on loads that had the whole
// compute(k) phase to land -> near-zero stall, one barrier per step.
__global__ __launch_bounds__(256) void gemm_fused_kernel(
    const unsigned short* __restrict__ xb,    // [8192][768] bf16
    const unsigned short* __restrict__ w1t,   // [768][768] bf16, n-major
    const float* __restrict__ b1,
    const float* __restrict__ s_arr,
    float* __restrict__ y)
{
    __shared__ unsigned short Al[2][128 * 64];   // 2 x 16 KB
    __shared__ unsigned short Bl[2][64 * 64];    // 2 x  8 KB
    const int b = blockIdx.x;
    const int c = b & 7, j = b >> 3;             // j in [0,96)
    const int m0 = (c * 8 + j / 12) * 128;
    const int n0 = (j % 12) * 64;
    const int tid  = threadIdx.x;
    const int lane = tid & 63;
    const int wave = tid >> 6;
    const int wm = wave >> 1, wn = wave & 1;
    const int l15 = lane & 15, quad = lane >> 4;

    // per-thread staging coords (precomputed once)
    const int rA0 = tid >> 3, jA0 = (tid & 7) ^ (rA0 & 7);

    f32x4 acc[4][2];
    #pragma unroll
    for (int i = 0; i < 4; ++i)
        #pragma unroll
        for (int jj = 0; jj < 2; ++jj)
            acc[i][jj] = (f32x4){0.f, 0.f, 0.f, 0.f};

    // stage k-step 0 into buffer 0
    {
        const int k0 = 0;
        #pragma unroll
        for (int i = 0; i < 4; ++i) {
            int ch = tid + i * 256;
            int r = ch >> 3, jg = (ch & 7) ^ (r & 7);
            async16(xb + (m0 + r) * DM + k0 + jg * 8, &Al[0][ch * 8]);
        }
        #pragma unroll
        for (int i = 0; i < 2; ++i) {
            int ch = tid + i * 256;
            int r = ch >> 3, jg = (ch & 7) ^ (r & 7);
            async16(w1t + (n0 + r) * DM + k0 + jg * 8, &Bl[0][ch * 8]);
        }
    }

    for (int step = 0; step < DM / 64; ++step) {
        const int cur = step & 1;
        __syncthreads();   // drains this step's loads (in flight since last compute)

        if (step + 1 < DM / 64) {
            const int k0 = (step + 1) * 64;
            const int nxt = cur ^ 1;
            #pragma unroll
            for (int i = 0; i < 4; ++i) {
                int ch = tid + i * 256;
                int r = ch >> 3, jg = (ch & 7) ^ (r & 7);
                async16(xb + (m0 + r) * DM + k0 + jg * 8, &Al[nxt][ch * 8]);
            }
            #pragma unroll
            for (int i = 0; i < 2; ++i) {
                int ch = tid + i * 256;
                int r = ch >> 3, jg = (ch & 7) ^ (r & 7);
                async16(w1t + (n0 + r) * DM + k0 + jg * 8, &Bl[nxt][ch * 8]);
            }
        }

        #pragma unroll
        for (int kk = 0; kk < 2; ++kk) {
            bf16x8 bfr[2];
            #pragma unroll
            for (int jj = 0; jj < 2; ++jj) {
                int rb = wn * 32 + jj * 16 + l15;
                int jb = (kk * 4 + quad) ^ (rb & 7);
                bfr[jj] = *(const bf16x8*)(&Bl[cur][rb * 64 + jb * 8]);
            }
            #pragma unroll
            for (int i = 0; i < 4; ++i) {
                int rr = wm * 64 + i * 16 + l15;
                int ja = (kk * 4 + quad) ^ (rr & 7);
                bf16x8 af = *(const bf16x8*)(&Al[cur][rr * 64 + ja * 8]);
                #pragma unroll
                for (int jj = 0; jj < 2; ++jj)
                    acc[i][jj] = __builtin_amdgcn_mfma_f32_16x16x32_bf16(
                        af, bfr[jj], acc[i][jj], 0, 0, 0);
            }
        }
    }

    // epilogue: C/D layout col = lane&15, row = quad*4 + reg
    #pragma unroll
    for (int i = 0; i < 4; ++i) {
        const int rowbase = m0 + wm * 64 + i * 16 + quad * 4;
        float4 s4 = *(const float4*)(s_arr + rowbase);
        #pragma unroll
        for (int jj = 0; jj < 2; ++jj) {
            int gcol = n0 + wn * 32 + jj * 16 + l15;
            float bias = b1[gcol];
            #pragma unroll
            for (int r = 0; r < 4; ++r) {
                int grow = rowbase + r;
                float v = acc[i][jj][r] + bias;
                float sp = (v > 20.f) ? v : log1pf(__expf(v));
                float xv = bf2f(xb[grow * DM + gcol]);
                float sv = (r == 0) ? s4.x : (r == 1) ? s4.y : (r == 2) ? s4.z : s4.w;
                y[grow * DM + gcol] = xv * sp * sv;
            }
        }
    }
    (void)rA0; (void)jA0;
}

extern "C" void kernel_launch(void* const* d_in, const int* in_sizes, int n_in,
                              void* d_out, int out_size, void* d_ws, size_t ws_size,
                              hipStream_t stream) {
    const float* x  = (const float*)d_in[0];
    const float* W1 = (const float*)d_in[1];
    const float* b1 = (const float*)d_in[2];
    const float* W2 = (const float*)d_in[3];
    const float* b2 = (const float*)d_in[4];
    const float* W3 = (const float*)d_in[5];
    const float* b3 = (const float*)d_in[6];
    // d_in[7] = A : unused (multiplied by h0 == 0 in the reference)
    float* y = (float*)d_out;

    unsigned short* xb   = (unsigned short*)d_ws;                      // 12,582,912 B
    unsigned short* w1t  = (unsigned short*)((char*)d_ws + 12582912);  //  1,179,648 B
    unsigned short* w23t = (unsigned short*)((char*)d_ws + 13762560);  //     49,152 B
    float*          sarr = (float*)((char*)d_ws + 13811712);           //     32,768 B

    prep_kernel<<<6752, 256, 0, stream>>>(x, W1, W2, W3, xb, w1t, w23t);
    sgemm_kernel<<<128, 256, 0, stream>>>(xb, w23t, b2, b3, sarr);
    gemm_fused_kernel<<<768, 256, 0, stream>>>(xb, w1t, b1, sarr, y);
}